// Round 7
// baseline (265.742 us; speedup 1.0000x reference)
//
#include <hip/hip_runtime.h>
#include <stdint.h>

typedef __bf16 v8bf __attribute__((ext_vector_type(8)));
typedef float  v4f  __attribute__((ext_vector_type(4)));

// 0.125 (1/sqrt(64)) * log2(e): folded into Q so attention uses exp2 directly.
#define QSCALE 0.18033688011112042f

// Async global -> LDS DMA, 16 B per lane; lds base wave-uniform, lane*16 scatter.
typedef __attribute__((address_space(3))) void lds_vp;
typedef const __attribute__((address_space(1))) void gbl_vp;
__device__ __forceinline__ void gl_lds16(const __bf16* g, __bf16* l) {
    __builtin_amdgcn_global_load_lds((gbl_vp*)g, (lds_vp*)l, 16, 0, 0);
}

__device__ __forceinline__ v8bf cvt8(const float* __restrict__ p) {
    float4 x = *reinterpret_cast<const float4*>(p);
    float4 y = *reinterpret_cast<const float4*>(p + 4);
    v8bf r;
    r[0] = (__bf16)x.x; r[1] = (__bf16)x.y; r[2] = (__bf16)x.z; r[3] = (__bf16)x.w;
    r[4] = (__bf16)y.x; r[5] = (__bf16)y.y; r[6] = (__bf16)y.z; r[7] = (__bf16)y.w;
    return r;
}

// 4 weight matrices (1024x1024 f32 -> bf16), grid (512,4).
__global__ __launch_bounds__(256) void cvt_w(
    const float* __restrict__ w0, const float* __restrict__ w1,
    const float* __restrict__ w2, const float* __restrict__ w3,
    __bf16* __restrict__ o0, __bf16* __restrict__ o1,
    __bf16* __restrict__ o2, __bf16* __restrict__ o3)
{
    const float* src; __bf16* dst;
    switch (blockIdx.y) {
        case 0: src = w0; dst = o0; break;
        case 1: src = w1; dst = o1; break;
        case 2: src = w2; dst = o2; break;
        default: src = w3; dst = o3; break;
    }
    size_t i = ((size_t)blockIdx.x * 256 + threadIdx.x) * 8;
    *reinterpret_cast<v8bf*>(dst + i) = cvt8(src + i);
}

// 3 activation inputs (4096x1024 f32 -> bf16), grid (2048,3).
__global__ __launch_bounds__(256) void cvt_in(
    const float* __restrict__ i0, const float* __restrict__ i1,
    const float* __restrict__ i2,
    __bf16* __restrict__ o0, __bf16* __restrict__ o1, __bf16* __restrict__ o2)
{
    const float* src; __bf16* dst;
    switch (blockIdx.y) {
        case 0: src = i0; dst = o0; break;
        case 1: src = i1; dst = o1; break;
        default: src = i2; dst = o2; break;
    }
    size_t i = ((size_t)blockIdx.x * 256 + threadIdx.x) * 8;
    *reinterpret_cast<v8bf*>(dst + i) = cvt8(src + i);
}

// LDS-staged GEMM body (m97 structure). Tile MT x 128, BK=64, 4 waves.
// XOR chunk swizzle: data chunk c of row r at LDS slot c^(r&7) -> ds_read_b128
// <=2-way bank-aliased (free), DMA stays contiguous per 8-lane row group.
template<int MT>
__device__ __forceinline__ void gemm_body(
    const __bf16* __restrict__ A, const __bf16* __restrict__ W,
    const float* __restrict__ bias, void* __restrict__ outp,
    int mode, float oscale, int bx, int by)
{
    constexpr int K = 1024, N = 1024;
    constexpr int WM = MT / 32;
    constexpr int AI = MT / 32;
    constexpr int BI = 4;
    __shared__ __align__(16) __bf16 As[MT * 64];
    __shared__ __align__(16) __bf16 Bs[128 * 64];

    const int lane = threadIdx.x & 63;
    const int wave = threadIdx.x >> 6;
    const int quad = lane >> 4;
    const int l15  = lane & 15;
    const int m_base = bx * MT;
    const int n_base = by * 128;
    const int wm = (wave & 1) * (MT / 2);
    const int wn = (wave >> 1) * 64;

    int arow[AI], acol[AI], brow[BI], bcol[BI];
    #pragma unroll
    for (int i = 0; i < AI; ++i) {
        int L = (i * 4 + wave) * 64 + lane;
        int r = L >> 3, s = L & 7;
        arow[i] = r; acol[i] = (s ^ (r & 7)) * 8;
    }
    #pragma unroll
    for (int i = 0; i < BI; ++i) {
        int L = (i * 4 + wave) * 64 + lane;
        int r = L >> 3, s = L & 7;
        brow[i] = r; bcol[i] = (s ^ (r & 7)) * 8;
    }

    v4f acc[WM][4];
    #pragma unroll
    for (int fa = 0; fa < WM; ++fa)
        #pragma unroll
        for (int fb = 0; fb < 4; ++fb) { v4f z = {0.f,0.f,0.f,0.f}; acc[fa][fb] = z; }

    for (int kb = 0; kb < K; kb += 64) {
        #pragma unroll
        for (int i = 0; i < AI; ++i)
            gl_lds16(A + (size_t)(m_base + arow[i]) * K + kb + acol[i],
                     &As[(size_t)(i * 4 + wave) * 512]);
        #pragma unroll
        for (int i = 0; i < BI; ++i)
            gl_lds16(W + (size_t)(n_base + brow[i]) * K + kb + bcol[i],
                     &Bs[(size_t)(i * 4 + wave) * 512]);
        __syncthreads();
        #pragma unroll
        for (int ks = 0; ks < 2; ++ks) {
            v8bf af[WM], bf[4];
            #pragma unroll
            for (int f = 0; f < WM; ++f) {
                const int R = wm + f * 16 + l15;
                const int slot = (ks * 4 + quad) ^ (R & 7);
                af[f] = *reinterpret_cast<const v8bf*>(&As[R * 64 + slot * 8]);
            }
            #pragma unroll
            for (int f = 0; f < 4; ++f) {
                const int R = wn + f * 16 + l15;
                const int slot = (ks * 4 + quad) ^ (R & 7);
                bf[f] = *reinterpret_cast<const v8bf*>(&Bs[R * 64 + slot * 8]);
            }
            #pragma unroll
            for (int fa = 0; fa < WM; ++fa)
                #pragma unroll
                for (int fb = 0; fb < 4; ++fb)
                    acc[fa][fb] = __builtin_amdgcn_mfma_f32_16x16x32_bf16(
                        af[fa], bf[fb], acc[fa][fb], 0, 0, 0);
        }
        __syncthreads();
    }

    #pragma unroll
    for (int fa = 0; fa < WM; ++fa)
        #pragma unroll
        for (int fb = 0; fb < 4; ++fb) {
            const int nc = n_base + wn + fb * 16 + l15;
            const float bval = bias[nc];
            #pragma unroll
            for (int r = 0; r < 4; ++r) {
                const int m = m_base + wm + fa * 16 + quad * 4 + r;
                const float v = (acc[fa][fb][r] + bval) * oscale;
                if (mode == 2) {
                    ((float*)outp)[(size_t)m * N + nc] = v;
                } else {
                    int b = m >> 11, n = m & 2047, h = nc >> 6, d = nc & 63;
                    size_t off = (mode == 0)
                        ? ((size_t)(b * 16 + h) * 2048 + n) * 64 + d
                        : ((size_t)(b * 16 + h) * 64 + d) * 2048 + n;
                    ((__bf16*)outp)[off] = (__bf16)v;
                }
            }
        }
}

// Fused QKV projections. 1D grid 768: id%8 = by -> same W n-slice per XCD.
__global__ __launch_bounds__(256) void qkv_gemm(
    const __bf16* __restrict__ Aq, const __bf16* __restrict__ Ak,
    const __bf16* __restrict__ Av,
    const __bf16* __restrict__ Wq, const __bf16* __restrict__ Wk,
    const __bf16* __restrict__ Wv,
    const float* __restrict__ bq, const float* __restrict__ bk,
    const float* __restrict__ bv,
    __bf16* __restrict__ Qo, __bf16* __restrict__ Ko, __bf16* __restrict__ Vo)
{
    const int id = blockIdx.x;
    const int by = id & 7;
    const int bx = (id >> 3) & 31;
    const int z  = id >> 8;

    const __bf16 *A, *W; const float* bias; __bf16* outp; float oscale; int mode;
    switch (z) {
        case 0:  A = Aq; W = Wq; bias = bq; outp = Qo; oscale = QSCALE; mode = 0; break;
        case 1:  A = Ak; W = Wk; bias = bk; outp = Ko; oscale = 1.0f;   mode = 0; break;
        default: A = Av; W = Wv; bias = bv; outp = Vo; oscale = 1.0f;   mode = 1; break;
    }
    gemm_body<128>(A, W, bias, outp, mode, oscale, bx, by);
}

// Final projection, f32 out. 1D grid 512: id%8 = by.
__global__ __launch_bounds__(256) void out_gemm(
    const __bf16* __restrict__ A, const __bf16* __restrict__ W,
    const float* __restrict__ bias, float* __restrict__ outp)
{
    const int by = blockIdx.x & 7;
    const int bx = blockIdx.x >> 3;
    gemm_body<64>(A, W, bias, outp, 2, 1.0f, bx, by);
}

// Flash attention, fixed-shift softmax, LDS-staged K/V.
// Block: 4 waves x 16 q-rows = 64 rows. 1D grid 1024: id%8 = bh%8 -> K/V slice
// L2-resident per XCD. Q,K: bf16 [b,h,2048,64]; V: bf16 [b,h,64,2048];
// O: bf16 [4096,1024].
__global__ __launch_bounds__(256) void attn_kernel(
    const __bf16* __restrict__ Q, const __bf16* __restrict__ Kb_,
    const __bf16* __restrict__ Vt, __bf16* __restrict__ O)
{
    __shared__ __align__(16) __bf16 Ks[64 * 64];
    __shared__ __align__(16) __bf16 Vs[64 * 64];
    __shared__ __align__(16) __bf16 p_lds[4][16][72];

    const int lane = threadIdx.x & 63;
    const int wave = threadIdx.x >> 6;
    const int quad = lane >> 4;
    const int l15  = lane & 15;
    const int bh = blockIdx.x & 31;   // id%8 = bh%8 -> XCD locality for K/V
    const int qt = blockIdx.x >> 5;   // 0..31 (64-row q tiles)
    const int b  = bh >> 4, h = bh & 15;

    const __bf16* Qh = Q   + (size_t)bh * 2048 * 64;
    const __bf16* Kh = Kb_ + (size_t)bh * 2048 * 64;
    const __bf16* Vh = Vt  + (size_t)bh * 64 * 2048;

    int srow[2], scol[2];
    #pragma unroll
    for (int i = 0; i < 2; ++i) {
        int L = (i * 4 + wave) * 64 + lane;
        int r = L >> 3, s = L & 7;
        srow[i] = r; scol[i] = (s ^ (r & 7)) * 8;
    }

    v8bf qf[2];
    #pragma unroll
    for (int ks = 0; ks < 2; ++ks)
        qf[ks] = *reinterpret_cast<const v8bf*>(
            Qh + (size_t)(qt * 64 + wave * 16 + l15) * 64 + ks * 32 + quad * 8);

    v4f o_acc[4];
    #pragma unroll
    for (int c = 0; c < 4; ++c) { v4f z = {0.f,0.f,0.f,0.f}; o_acc[c] = z; }
    float l_r[4];
    #pragma unroll
    for (int r = 0; r < 4; ++r) l_r[r] = 0.f;

    for (int kt = 0; kt < 32; ++kt) {
        #pragma unroll
        for (int i = 0; i < 2; ++i) {
            gl_lds16(Kh + (size_t)(kt * 64 + srow[i]) * 64 + scol[i],
                     &Ks[(size_t)(i * 4 + wave) * 512]);
            gl_lds16(Vh + (size_t)srow[i] * 2048 + kt * 64 + scol[i],
                     &Vs[(size_t)(i * 4 + wave) * 512]);
        }
        __syncthreads();

        // S = Q @ K^T (scores in log2 domain via Q pre-scale).
        v4f s_t[4];
        #pragma unroll
        for (int c = 0; c < 4; ++c) { v4f z = {0.f,0.f,0.f,0.f}; s_t[c] = z; }
        #pragma unroll
        for (int ks = 0; ks < 2; ++ks) {
            v8bf kf[4];
            #pragma unroll
            for (int c = 0; c < 4; ++c) {
                const int R = c * 16 + l15;
                const int slot = (ks * 4 + quad) ^ (R & 7);
                kf[c] = *reinterpret_cast<const v8bf*>(&Ks[R * 64 + slot * 8]);
            }
            #pragma unroll
            for (int c = 0; c < 4; ++c)
                s_t[c] = __builtin_amdgcn_mfma_f32_16x16x32_bf16(qf[ks], kf[c], s_t[c], 0, 0, 0);
        }

        // p = 2^s; per-lane row-sum partials; stage P (wave-private, no barrier).
        #pragma unroll
        for (int r = 0; r < 4; ++r) {
            const float p0 = __builtin_exp2f(s_t[0][r]);
            const float p1 = __builtin_exp2f(s_t[1][r]);
            const float p2 = __builtin_exp2f(s_t[2][r]);
            const float p3 = __builtin_exp2f(s_t[3][r]);
            l_r[r] += (p0 + p1) + (p2 + p3);
            p_lds[wave][quad * 4 + r][0 * 16 + l15] = (__bf16)p0;
            p_lds[wave][quad * 4 + r][1 * 16 + l15] = (__bf16)p1;
            p_lds[wave][quad * 4 + r][2 * 16 + l15] = (__bf16)p2;
            p_lds[wave][quad * 4 + r][3 * 16 + l15] = (__bf16)p3;
        }

        // O += P @ V
        #pragma unroll
        for (int ks = 0; ks < 2; ++ks) {
            v8bf vf[4];
            #pragma unroll
            for (int c = 0; c < 4; ++c) {
                const int R = c * 16 + l15;
                const int slot = (ks * 4 + quad) ^ (R & 7);
                vf[c] = *reinterpret_cast<const v8bf*>(&Vs[R * 64 + slot * 8]);
            }
            v8bf pf = *reinterpret_cast<const v8bf*>(&p_lds[wave][l15][ks * 32 + quad * 8]);
            #pragma unroll
            for (int c = 0; c < 4; ++c)
                o_acc[c] = __builtin_amdgcn_mfma_f32_16x16x32_bf16(pf, vf[c], o_acc[c], 0, 0, 0);
        }
        __syncthreads();
    }

    // Reduce l across 16 lanes per row; write O bf16 [b*2048+q, h*64+d].
    #pragma unroll
    for (int r = 0; r < 4; ++r) {
        float l = l_r[r];
        #pragma unroll
        for (int off = 1; off < 16; off <<= 1)
            l += __shfl_xor(l, off, 16);
        const float inv_l = 1.0f / l;
        const int qr = qt * 64 + wave * 16 + quad * 4 + r;
        #pragma unroll
        for (int c = 0; c < 4; ++c) {
            const int col = h * 64 + c * 16 + l15;
            O[(size_t)(b * 2048 + qr) * 1024 + col] = (__bf16)(o_acc[c][r] * inv_l);
        }
    }
}

extern "C" void kernel_launch(void* const* d_in, const int* in_sizes, int n_in,
                              void* d_out, int out_size, void* d_ws, size_t ws_size,
                              hipStream_t stream) {
    const float* q_in = (const float*)d_in[0];
    const float* k_in = (const float*)d_in[1];
    const float* v_in = (const float*)d_in[2];
    const float* Wq = (const float*)d_in[3];
    const float* bq = (const float*)d_in[4];
    const float* Wk = (const float*)d_in[5];
    const float* bk = (const float*)d_in[6];
    const float* Wv = (const float*)d_in[7];
    const float* bv = (const float*)d_in[8];
    const float* Wo = (const float*)d_in[9];
    const float* bo = (const float*)d_in[10];
    float* out = (float*)d_out;

    // Workspace (bf16 elements), 56 MiB. Ob aliases Abq (consumed before attn).
    __bf16* ws  = (__bf16*)d_ws;
    __bf16* Abq = ws;                  // [4096,1024]
    __bf16* Abk = Abq + 4194304;
    __bf16* Abv = Abk + 4194304;
    __bf16* Qb  = Abv + 4194304;       // [2,16,2048,64]
    __bf16* Kb  = Qb  + 4194304;
    __bf16* Vb  = Kb  + 4194304;       // [2,16,64,2048]
    __bf16* Wqb = Vb  + 4194304;       // [1024,1024] x4
    __bf16* Wkb = Wqb + 1048576;
    __bf16* Wvb = Wkb + 1048576;
    __bf16* Wob = Wvb + 1048576;
    __bf16* Ob  = Abq;                 // alias

    cvt_w<<<dim3(512, 4), 256, 0, stream>>>(Wq, Wk, Wv, Wo, Wqb, Wkb, Wvb, Wob);
    cvt_in<<<dim3(2048, 3), 256, 0, stream>>>(q_in, k_in, v_in, Abq, Abk, Abv);

    qkv_gemm<<<768, 256, 0, stream>>>(
        Abq, Abk, Abv, Wqb, Wkb, Wvb, bq, bk, bv, Qb, Kb, Vb);

    attn_kernel<<<1024, 256, 0, stream>>>(Qb, Kb, Vb, Ob);

    out_gemm<<<512, 256, 0, stream>>>(Ob, Wob, bo, out);
}

// Round 8
// 260.710 us; speedup vs baseline: 1.0193x; 1.0193x over previous
//
#include <hip/hip_runtime.h>
#include <stdint.h>

typedef __bf16 v8bf __attribute__((ext_vector_type(8)));
typedef float  v4f  __attribute__((ext_vector_type(4)));

// 0.125 (1/sqrt(64)) * log2(e): folded into Q so attention uses exp2 directly.
#define QSCALE 0.18033688011112042f

__device__ __forceinline__ v8bf cvt8(const float* __restrict__ p) {
    float4 x = *reinterpret_cast<const float4*>(p);
    float4 y = *reinterpret_cast<const float4*>(p + 4);
    v8bf r;
    r[0] = (__bf16)x.x; r[1] = (__bf16)x.y; r[2] = (__bf16)x.z; r[3] = (__bf16)x.w;
    r[4] = (__bf16)y.x; r[5] = (__bf16)y.y; r[6] = (__bf16)y.z; r[7] = (__bf16)y.w;
    return r;
}

// 4 weight matrices (1024x1024 f32 -> bf16), grid (512,4).
__global__ __launch_bounds__(256) void cvt_w(
    const float* __restrict__ w0, const float* __restrict__ w1,
    const float* __restrict__ w2, const float* __restrict__ w3,
    __bf16* __restrict__ o0, __bf16* __restrict__ o1,
    __bf16* __restrict__ o2, __bf16* __restrict__ o3)
{
    const float* src; __bf16* dst;
    switch (blockIdx.y) {
        case 0: src = w0; dst = o0; break;
        case 1: src = w1; dst = o1; break;
        case 2: src = w2; dst = o2; break;
        default: src = w3; dst = o3; break;
    }
    size_t i = ((size_t)blockIdx.x * 256 + threadIdx.x) * 8;
    *reinterpret_cast<v8bf*>(dst + i) = cvt8(src + i);
}

// 3 activation inputs (4096x1024 f32 -> bf16), grid (2048,3).
__global__ __launch_bounds__(256) void cvt_in(
    const float* __restrict__ i0, const float* __restrict__ i1,
    const float* __restrict__ i2,
    __bf16* __restrict__ o0, __bf16* __restrict__ o1, __bf16* __restrict__ o2)
{
    const float* src; __bf16* dst;
    switch (blockIdx.y) {
        case 0: src = i0; dst = o0; break;
        case 1: src = i1; dst = o1; break;
        default: src = i2; dst = o2; break;
    }
    size_t i = ((size_t)blockIdx.x * 256 + threadIdx.x) * 8;
    *reinterpret_cast<v8bf*>(dst + i) = cvt8(src + i);
}

// Register-prefetch pipelined GEMM. Tile MT x 128, BK=64, 4 waves, single LDS buf.
// Pipeline: ds_write staged regs -> barrier -> issue global loads for next K-tile
// (in flight across compute) -> ds_read/MFMA -> barrier.
// XOR chunk swizzle: chunk c of row r at LDS slot c^(r&7): ds_read_b128 <=2-way.
template<int MT>
__device__ __forceinline__ void gemm_body(
    const __bf16* __restrict__ A, const __bf16* __restrict__ W,
    const float* __restrict__ bias, void* __restrict__ outp,
    int mode, float oscale, int bx, int by)
{
    constexpr int K = 1024, N = 1024;
    constexpr int WM = MT / 32;
    constexpr int AI = MT / 32;
    constexpr int BI = 4;
    __shared__ __align__(16) __bf16 As[MT * 64];
    __shared__ __align__(16) __bf16 Bs[128 * 64];

    const int lane = threadIdx.x & 63;
    const int wave = threadIdx.x >> 6;
    const int quad = lane >> 4;
    const int l15  = lane & 15;
    const int m_base = bx * MT;
    const int n_base = by * 128;
    const int wm = (wave & 1) * (MT / 2);
    const int wn = (wave >> 1) * 64;

    int arow[AI], acol[AI], brow[BI], bcol[BI];
    #pragma unroll
    for (int i = 0; i < AI; ++i) {
        int L = (i * 4 + wave) * 64 + lane;
        int r = L >> 3, s = L & 7;
        arow[i] = r; acol[i] = (s ^ (r & 7)) * 8;
    }
    #pragma unroll
    for (int i = 0; i < BI; ++i) {
        int L = (i * 4 + wave) * 64 + lane;
        int r = L >> 3, s = L & 7;
        brow[i] = r; bcol[i] = (s ^ (r & 7)) * 8;
    }

    // Prologue: stage K-tile 0 into registers.
    v8bf areg[AI], wreg[BI];
    #pragma unroll
    for (int i = 0; i < AI; ++i)
        areg[i] = *reinterpret_cast<const v8bf*>(A + (size_t)(m_base + arow[i]) * K + acol[i]);
    #pragma unroll
    for (int i = 0; i < BI; ++i)
        wreg[i] = *reinterpret_cast<const v8bf*>(W + (size_t)(n_base + brow[i]) * K + bcol[i]);

    v4f acc[WM][4];
    #pragma unroll
    for (int fa = 0; fa < WM; ++fa)
        #pragma unroll
        for (int fb = 0; fb < 4; ++fb) { v4f z = {0.f,0.f,0.f,0.f}; acc[fa][fb] = z; }

    for (int kb = 0; kb < K; kb += 64) {
        // Commit staged regs to LDS.
        #pragma unroll
        for (int i = 0; i < AI; ++i)
            *reinterpret_cast<v8bf*>(&As[(i * 4 + wave) * 512 + lane * 8]) = areg[i];
        #pragma unroll
        for (int i = 0; i < BI; ++i)
            *reinterpret_cast<v8bf*>(&Bs[(i * 4 + wave) * 512 + lane * 8]) = wreg[i];
        __syncthreads();

        // Issue next tile's global loads (wrap on last iter, wasted but branchless).
        const int kn = (kb + 64) & 1023;
        #pragma unroll
        for (int i = 0; i < AI; ++i)
            areg[i] = *reinterpret_cast<const v8bf*>(A + (size_t)(m_base + arow[i]) * K + kn + acol[i]);
        #pragma unroll
        for (int i = 0; i < BI; ++i)
            wreg[i] = *reinterpret_cast<const v8bf*>(W + (size_t)(n_base + brow[i]) * K + kn + bcol[i]);

        #pragma unroll
        for (int ks = 0; ks < 2; ++ks) {
            v8bf af[WM], bf[4];
            #pragma unroll
            for (int f = 0; f < WM; ++f) {
                const int R = wm + f * 16 + l15;
                const int slot = (ks * 4 + quad) ^ (R & 7);
                af[f] = *reinterpret_cast<const v8bf*>(&As[R * 64 + slot * 8]);
            }
            #pragma unroll
            for (int f = 0; f < 4; ++f) {
                const int R = wn + f * 16 + l15;
                const int slot = (ks * 4 + quad) ^ (R & 7);
                bf[f] = *reinterpret_cast<const v8bf*>(&Bs[R * 64 + slot * 8]);
            }
            #pragma unroll
            for (int fa = 0; fa < WM; ++fa)
                #pragma unroll
                for (int fb = 0; fb < 4; ++fb)
                    acc[fa][fb] = __builtin_amdgcn_mfma_f32_16x16x32_bf16(
                        af[fa], bf[fb], acc[fa][fb], 0, 0, 0);
        }
        __syncthreads();
    }

    #pragma unroll
    for (int fa = 0; fa < WM; ++fa)
        #pragma unroll
        for (int fb = 0; fb < 4; ++fb) {
            const int nc = n_base + wn + fb * 16 + l15;
            const float bval = bias[nc];
            #pragma unroll
            for (int r = 0; r < 4; ++r) {
                const int m = m_base + wm + fa * 16 + quad * 4 + r;
                const float v = (acc[fa][fb][r] + bval) * oscale;
                if (mode == 2) {
                    ((float*)outp)[(size_t)m * N + nc] = v;
                } else {
                    int b = m >> 11, n = m & 2047, h = nc >> 6, d = nc & 63;
                    size_t off = (mode == 0)
                        ? ((size_t)(b * 16 + h) * 2048 + n) * 64 + d
                        : ((size_t)(b * 16 + h) * 64 + d) * 2048 + n;
                    ((__bf16*)outp)[off] = (__bf16)v;
                }
            }
        }
}

// Fused QKV projections. 1D grid 768: id%8 = by -> same W n-slice per XCD.
__global__ __launch_bounds__(256) void qkv_gemm(
    const __bf16* __restrict__ Aq, const __bf16* __restrict__ Ak,
    const __bf16* __restrict__ Av,
    const __bf16* __restrict__ Wq, const __bf16* __restrict__ Wk,
    const __bf16* __restrict__ Wv,
    const float* __restrict__ bq, const float* __restrict__ bk,
    const float* __restrict__ bv,
    __bf16* __restrict__ Qo, __bf16* __restrict__ Ko, __bf16* __restrict__ Vo)
{
    const int id = blockIdx.x;
    const int by = id & 7;
    const int bx = (id >> 3) & 31;
    const int z  = id >> 8;

    const __bf16 *A, *W; const float* bias; __bf16* outp; float oscale; int mode;
    switch (z) {
        case 0:  A = Aq; W = Wq; bias = bq; outp = Qo; oscale = QSCALE; mode = 0; break;
        case 1:  A = Ak; W = Wk; bias = bk; outp = Ko; oscale = 1.0f;   mode = 0; break;
        default: A = Av; W = Wv; bias = bv; outp = Vo; oscale = 1.0f;   mode = 1; break;
    }
    gemm_body<128>(A, W, bias, outp, mode, oscale, bx, by);
}

// Final projection, f32 out. 1D grid 512: id%8 = by.
__global__ __launch_bounds__(256) void out_gemm(
    const __bf16* __restrict__ A, const __bf16* __restrict__ W,
    const float* __restrict__ bias, float* __restrict__ outp)
{
    const int by = blockIdx.x & 7;
    const int bx = blockIdx.x >> 3;
    gemm_body<64>(A, W, bias, outp, 2, 1.0f, bx, by);
}

// Flash attention, fixed-shift softmax, register-prefetch pipelined K/V staging.
// Block: 4 waves x 16 q-rows = 64 rows. 1D grid 1024: id%8 = bh%8 (K/V XCD-local).
// Q,K: bf16 [b,h,2048,64]; V: bf16 [b,h,64,2048]; O: bf16 [4096,1024].
__global__ __launch_bounds__(256) void attn_kernel(
    const __bf16* __restrict__ Q, const __bf16* __restrict__ Kb_,
    const __bf16* __restrict__ Vt, __bf16* __restrict__ O)
{
    __shared__ __align__(16) __bf16 Ks[64 * 64];
    __shared__ __align__(16) __bf16 Vs[64 * 64];
    __shared__ __align__(16) __bf16 p_lds[4][16][72];

    const int lane = threadIdx.x & 63;
    const int wave = threadIdx.x >> 6;
    const int quad = lane >> 4;
    const int l15  = lane & 15;
    const int bh = blockIdx.x & 31;   // id%8 = bh%8 -> XCD locality for K/V
    const int qt = blockIdx.x >> 5;   // 0..31
    const int b  = bh >> 4, h = bh & 15;

    const __bf16* Qh = Q   + (size_t)bh * 2048 * 64;
    const __bf16* Kh = Kb_ + (size_t)bh * 2048 * 64;
    const __bf16* Vh = Vt  + (size_t)bh * 64 * 2048;

    int srow[2], scol[2];
    #pragma unroll
    for (int i = 0; i < 2; ++i) {
        int L = (i * 4 + wave) * 64 + lane;
        int r = L >> 3, s = L & 7;
        srow[i] = r; scol[i] = (s ^ (r & 7)) * 8;
    }

    v8bf qf[2];
    #pragma unroll
    for (int ks = 0; ks < 2; ++ks)
        qf[ks] = *reinterpret_cast<const v8bf*>(
            Qh + (size_t)(qt * 64 + wave * 16 + l15) * 64 + ks * 32 + quad * 8);

    // Prologue: stage kt=0 into registers.
    v8bf kreg[2], vreg[2];
    #pragma unroll
    for (int i = 0; i < 2; ++i) {
        kreg[i] = *reinterpret_cast<const v8bf*>(Kh + (size_t)srow[i] * 64 + scol[i]);
        vreg[i] = *reinterpret_cast<const v8bf*>(Vh + (size_t)srow[i] * 2048 + scol[i]);
    }

    v4f o_acc[4];
    #pragma unroll
    for (int c = 0; c < 4; ++c) { v4f z = {0.f,0.f,0.f,0.f}; o_acc[c] = z; }
    float l_r[4];
    #pragma unroll
    for (int r = 0; r < 4; ++r) l_r[r] = 0.f;

    for (int kt = 0; kt < 32; ++kt) {
        // Commit staged regs to LDS.
        #pragma unroll
        for (int i = 0; i < 2; ++i) {
            *reinterpret_cast<v8bf*>(&Ks[(i * 4 + wave) * 512 + lane * 8]) = kreg[i];
            *reinterpret_cast<v8bf*>(&Vs[(i * 4 + wave) * 512 + lane * 8]) = vreg[i];
        }
        __syncthreads();

        // Issue kt+1 global loads (in flight across the whole compute phase).
        const int ktn = (kt + 1) & 31;
        #pragma unroll
        for (int i = 0; i < 2; ++i) {
            kreg[i] = *reinterpret_cast<const v8bf*>(
                Kh + (size_t)(ktn * 64 + srow[i]) * 64 + scol[i]);
            vreg[i] = *reinterpret_cast<const v8bf*>(
                Vh + (size_t)srow[i] * 2048 + ktn * 64 + scol[i]);
        }

        // S = Q @ K^T (scores in log2 domain via Q pre-scale).
        v4f s_t[4];
        #pragma unroll
        for (int c = 0; c < 4; ++c) { v4f z = {0.f,0.f,0.f,0.f}; s_t[c] = z; }
        #pragma unroll
        for (int ks = 0; ks < 2; ++ks) {
            v8bf kf[4];
            #pragma unroll
            for (int c = 0; c < 4; ++c) {
                const int R = c * 16 + l15;
                const int slot = (ks * 4 + quad) ^ (R & 7);
                kf[c] = *reinterpret_cast<const v8bf*>(&Ks[R * 64 + slot * 8]);
            }
            #pragma unroll
            for (int c = 0; c < 4; ++c)
                s_t[c] = __builtin_amdgcn_mfma_f32_16x16x32_bf16(qf[ks], kf[c], s_t[c], 0, 0, 0);
        }

        // p = 2^s; per-lane row-sum partials; stage P (wave-private, no barrier).
        #pragma unroll
        for (int r = 0; r < 4; ++r) {
            const float p0 = __builtin_exp2f(s_t[0][r]);
            const float p1 = __builtin_exp2f(s_t[1][r]);
            const float p2 = __builtin_exp2f(s_t[2][r]);
            const float p3 = __builtin_exp2f(s_t[3][r]);
            l_r[r] += (p0 + p1) + (p2 + p3);
            p_lds[wave][quad * 4 + r][0 * 16 + l15] = (__bf16)p0;
            p_lds[wave][quad * 4 + r][1 * 16 + l15] = (__bf16)p1;
            p_lds[wave][quad * 4 + r][2 * 16 + l15] = (__bf16)p2;
            p_lds[wave][quad * 4 + r][3 * 16 + l15] = (__bf16)p3;
        }

        // O += P @ V
        #pragma unroll
        for (int ks = 0; ks < 2; ++ks) {
            v8bf vf[4];
            #pragma unroll
            for (int c = 0; c < 4; ++c) {
                const int R = c * 16 + l15;
                const int slot = (ks * 4 + quad) ^ (R & 7);
                vf[c] = *reinterpret_cast<const v8bf*>(&Vs[R * 64 + slot * 8]);
            }
            v8bf pf = *reinterpret_cast<const v8bf*>(&p_lds[wave][l15][ks * 32 + quad * 8]);
            #pragma unroll
            for (int c = 0; c < 4; ++c)
                o_acc[c] = __builtin_amdgcn_mfma_f32_16x16x32_bf16(pf, vf[c], o_acc[c], 0, 0, 0);
        }
        __syncthreads();
    }

    // Reduce l across 16 lanes per row; write O bf16 [b*2048+q, h*64+d].
    #pragma unroll
    for (int r = 0; r < 4; ++r) {
        float l = l_r[r];
        #pragma unroll
        for (int off = 1; off < 16; off <<= 1)
            l += __shfl_xor(l, off, 16);
        const float inv_l = 1.0f / l;
        const int qr = qt * 64 + wave * 16 + quad * 4 + r;
        #pragma unroll
        for (int c = 0; c < 4; ++c) {
            const int col = h * 64 + c * 16 + l15;
            O[(size_t)(b * 2048 + qr) * 1024 + col] = (__bf16)(o_acc[c][r] * inv_l);
        }
    }
}

extern "C" void kernel_launch(void* const* d_in, const int* in_sizes, int n_in,
                              void* d_out, int out_size, void* d_ws, size_t ws_size,
                              hipStream_t stream) {
    const float* q_in = (const float*)d_in[0];
    const float* k_in = (const float*)d_in[1];
    const float* v_in = (const float*)d_in[2];
    const float* Wq = (const float*)d_in[3];
    const float* bq = (const float*)d_in[4];
    const float* Wk = (const float*)d_in[5];
    const float* bk = (const float*)d_in[6];
    const float* Wv = (const float*)d_in[7];
    const float* bv = (const float*)d_in[8];
    const float* Wo = (const float*)d_in[9];
    const float* bo = (const float*)d_in[10];
    float* out = (float*)d_out;

    // Workspace (bf16 elements), 56 MiB. Ob aliases Abq (consumed before attn).
    __bf16* ws  = (__bf16*)d_ws;
    __bf16* Abq = ws;                  // [4096,1024]
    __bf16* Abk = Abq + 4194304;
    __bf16* Abv = Abk + 4194304;
    __bf16* Qb  = Abv + 4194304;       // [2,16,2048,64]
    __bf16* Kb  = Qb  + 4194304;
    __bf16* Vb  = Kb  + 4194304;       // [2,16,64,2048]
    __bf16* Wqb = Vb  + 4194304;       // [1024,1024] x4
    __bf16* Wkb = Wqb + 1048576;
    __bf16* Wvb = Wkb + 1048576;
    __bf16* Wob = Wvb + 1048576;
    __bf16* Ob  = Abq;                 // alias

    cvt_w<<<dim3(512, 4), 256, 0, stream>>>(Wq, Wk, Wv, Wo, Wqb, Wkb, Wvb, Wob);
    cvt_in<<<dim3(2048, 3), 256, 0, stream>>>(q_in, k_in, v_in, Abq, Abk, Abv);

    qkv_gemm<<<768, 256, 0, stream>>>(
        Abq, Abk, Abv, Wqb, Wkb, Wvb, bq, bk, bv, Qb, Kb, Vb);

    attn_kernel<<<1024, 256, 0, stream>>>(Qb, Kb, Vb, Ob);

    out_gemm<<<512, 256, 0, stream>>>(Ob, Wob, bo, out);
}

// Round 9
// 254.674 us; speedup vs baseline: 1.0435x; 1.0237x over previous
//
#include <hip/hip_runtime.h>
#include <stdint.h>

typedef __bf16 v8bf __attribute__((ext_vector_type(8)));
typedef float  v4f  __attribute__((ext_vector_type(4)));

// 0.125 (1/sqrt(64)) * log2(e): folded into Q so attention uses exp2 directly.
#define QSCALE 0.18033688011112042f

// Async global -> LDS DMA, 16 B/lane; LDS base wave-uniform, lane*16 scatter.
typedef __attribute__((address_space(3))) void lds_vp;
typedef const __attribute__((address_space(1))) void gbl_vp;
__device__ __forceinline__ void gl_lds16(const __bf16* g, __bf16* l) {
    __builtin_amdgcn_global_load_lds((gbl_vp*)g, (lds_vp*)l, 16, 0, 0);
}

__device__ __forceinline__ v8bf cvt8(const float* __restrict__ p) {
    float4 x = *reinterpret_cast<const float4*>(p);
    float4 y = *reinterpret_cast<const float4*>(p + 4);
    v8bf r;
    r[0] = (__bf16)x.x; r[1] = (__bf16)x.y; r[2] = (__bf16)x.z; r[3] = (__bf16)x.w;
    r[4] = (__bf16)y.x; r[5] = (__bf16)y.y; r[6] = (__bf16)y.z; r[7] = (__bf16)y.w;
    return r;
}

// 4 weight matrices (1024x1024 f32 -> bf16), grid (512,4).
__global__ __launch_bounds__(256) void cvt_w(
    const float* __restrict__ w0, const float* __restrict__ w1,
    const float* __restrict__ w2, const float* __restrict__ w3,
    __bf16* __restrict__ o0, __bf16* __restrict__ o1,
    __bf16* __restrict__ o2, __bf16* __restrict__ o3)
{
    const float* src; __bf16* dst;
    switch (blockIdx.y) {
        case 0: src = w0; dst = o0; break;
        case 1: src = w1; dst = o1; break;
        case 2: src = w2; dst = o2; break;
        default: src = w3; dst = o3; break;
    }
    size_t i = ((size_t)blockIdx.x * 256 + threadIdx.x) * 8;
    *reinterpret_cast<v8bf*>(dst + i) = cvt8(src + i);
}

// 3 activation inputs (4096x1024 f32 -> bf16), grid (2048,3).
__global__ __launch_bounds__(256) void cvt_in(
    const float* __restrict__ i0, const float* __restrict__ i1,
    const float* __restrict__ i2,
    __bf16* __restrict__ o0, __bf16* __restrict__ o1, __bf16* __restrict__ o2)
{
    const float* src; __bf16* dst;
    switch (blockIdx.y) {
        case 0: src = i0; dst = o0; break;
        case 1: src = i1; dst = o1; break;
        default: src = i2; dst = o2; break;
    }
    size_t i = ((size_t)blockIdx.x * 256 + threadIdx.x) * 8;
    *reinterpret_cast<v8bf*>(dst + i) = cvt8(src + i);
}

// Double-buffered DMA GEMM. Tile 128m x 64n, BK=64, 4 waves (wave: 64m x 32n).
// Pipeline: [stage kb+1 into buf^1 via global_load_lds] while [compute buf];
// ONE barrier per iter covers both DMA completion and read/write hazards.
// XOR chunk swizzle: global chunk c of row r lands at LDS slot c^(r&7)
// -> fragment ds_read_b128 <=2-way bank-aliased (free per m136).
// mode 0: out bf16 [((b*16+h)*2048+n)*64+d]; mode 1: out bf16 [((b*16+h)*64+d)*2048+n];
// mode 2: out f32 [m*1024+nc].
__device__ __forceinline__ void gemm_body(
    const __bf16* __restrict__ A, const __bf16* __restrict__ W,
    const float* __restrict__ bias, void* __restrict__ outp,
    int mode, float oscale, int bx, int by)
{
    constexpr int K = 1024, N = 1024;
    __shared__ __align__(16) __bf16 As[2][128 * 64];
    __shared__ __align__(16) __bf16 Bs[2][64 * 64];

    const int lane = threadIdx.x & 63;
    const int wave = threadIdx.x >> 6;
    const int quad = lane >> 4;
    const int l15  = lane & 15;
    const int m_base = bx * 128;
    const int n_base = by * 64;
    const int wm = (wave & 1) * 64;
    const int wn = (wave >> 1) * 32;

    // Staging coords: A 16KB -> 4 insts/wave; B 8KB -> 2 insts/wave.
    int arow[4], acol[4], brow[2], bcol[2];
    #pragma unroll
    for (int i = 0; i < 4; ++i) {
        int L = (i * 4 + wave) * 64 + lane;
        int r = L >> 3, s = L & 7;
        arow[i] = r; acol[i] = (s ^ (r & 7)) * 8;
    }
    #pragma unroll
    for (int i = 0; i < 2; ++i) {
        int L = (i * 4 + wave) * 64 + lane;
        int r = L >> 3, s = L & 7;
        brow[i] = r; bcol[i] = (s ^ (r & 7)) * 8;
    }

    v4f acc[4][2];
    #pragma unroll
    for (int f = 0; f < 4; ++f)
        #pragma unroll
        for (int g = 0; g < 2; ++g) { v4f z = {0.f,0.f,0.f,0.f}; acc[f][g] = z; }

    // Prologue: stage kb=0 into buf 0.
    #pragma unroll
    for (int i = 0; i < 4; ++i)
        gl_lds16(A + (size_t)(m_base + arow[i]) * K + acol[i],
                 &As[0][(i * 4 + wave) * 512]);
    #pragma unroll
    for (int i = 0; i < 2; ++i)
        gl_lds16(W + (size_t)(n_base + brow[i]) * K + bcol[i],
                 &Bs[0][(i * 4 + wave) * 512]);
    __syncthreads();

    for (int it = 0; it < 16; ++it) {
        const int cur = it & 1, nxt = cur ^ 1;
        const int kn = ((it + 1) & 15) * 64;   // wraps on last iter (wasted DMA)
        #pragma unroll
        for (int i = 0; i < 4; ++i)
            gl_lds16(A + (size_t)(m_base + arow[i]) * K + kn + acol[i],
                     &As[nxt][(i * 4 + wave) * 512]);
        #pragma unroll
        for (int i = 0; i < 2; ++i)
            gl_lds16(W + (size_t)(n_base + brow[i]) * K + kn + bcol[i],
                     &Bs[nxt][(i * 4 + wave) * 512]);

        #pragma unroll
        for (int ks = 0; ks < 2; ++ks) {
            v8bf af[4], bf[2];
            #pragma unroll
            for (int f = 0; f < 4; ++f) {
                const int R = wm + f * 16 + l15;
                const int slot = (ks * 4 + quad) ^ (R & 7);
                af[f] = *reinterpret_cast<const v8bf*>(&As[cur][R * 64 + slot * 8]);
            }
            #pragma unroll
            for (int g = 0; g < 2; ++g) {
                const int R = wn + g * 16 + l15;
                const int slot = (ks * 4 + quad) ^ (R & 7);
                bf[g] = *reinterpret_cast<const v8bf*>(&Bs[cur][R * 64 + slot * 8]);
            }
            #pragma unroll
            for (int f = 0; f < 4; ++f)
                #pragma unroll
                for (int g = 0; g < 2; ++g)
                    acc[f][g] = __builtin_amdgcn_mfma_f32_16x16x32_bf16(
                        af[f], bf[g], acc[f][g], 0, 0, 0);
        }
        __syncthreads();   // DMA for it+1 done + all reads of cur done
    }

    #pragma unroll
    for (int f = 0; f < 4; ++f)
        #pragma unroll
        for (int g = 0; g < 2; ++g) {
            const int nc = n_base + wn + g * 16 + l15;
            const float bval = bias[nc];
            #pragma unroll
            for (int r = 0; r < 4; ++r) {
                const int m = m_base + wm + f * 16 + quad * 4 + r;
                const float v = (acc[f][g][r] + bval) * oscale;
                if (mode == 2) {
                    ((float*)outp)[(size_t)m * N + nc] = v;
                } else {
                    int b = m >> 11, n = m & 2047, h = nc >> 6, d = nc & 63;
                    size_t off = (mode == 0)
                        ? ((size_t)(b * 16 + h) * 2048 + n) * 64 + d
                        : ((size_t)(b * 16 + h) * 64 + d) * 2048 + n;
                    ((__bf16*)outp)[off] = (__bf16)v;
                }
            }
        }
}

// Fused QKV projections. 1D grid 1536: id%16 = by (by%8 -> XCD-local W slice).
__global__ __launch_bounds__(256) void qkv_gemm(
    const __bf16* __restrict__ Aq, const __bf16* __restrict__ Ak,
    const __bf16* __restrict__ Av,
    const __bf16* __restrict__ Wq, const __bf16* __restrict__ Wk,
    const __bf16* __restrict__ Wv,
    const float* __restrict__ bq, const float* __restrict__ bk,
    const float* __restrict__ bv,
    __bf16* __restrict__ Qo, __bf16* __restrict__ Ko, __bf16* __restrict__ Vo)
{
    const int id = blockIdx.x;
    const int by = id & 15;
    const int bx = (id >> 4) & 31;
    const int z  = id >> 9;

    const __bf16 *A, *W; const float* bias; __bf16* outp; float oscale; int mode;
    switch (z) {
        case 0:  A = Aq; W = Wq; bias = bq; outp = Qo; oscale = QSCALE; mode = 0; break;
        case 1:  A = Ak; W = Wk; bias = bk; outp = Ko; oscale = 1.0f;   mode = 0; break;
        default: A = Av; W = Wv; bias = bv; outp = Vo; oscale = 1.0f;   mode = 1; break;
    }
    gemm_body(A, W, bias, outp, mode, oscale, bx, by);
}

// Final projection, f32 out. 1D grid 512: id%16 = by.
__global__ __launch_bounds__(256) void out_gemm(
    const __bf16* __restrict__ A, const __bf16* __restrict__ W,
    const float* __restrict__ bias, float* __restrict__ outp)
{
    const int by = blockIdx.x & 15;
    const int bx = blockIdx.x >> 4;
    gemm_body(A, W, bias, outp, 2, 1.0f, bx, by);
}

// Flash attention, fixed-shift softmax, double-buffered DMA K/V staging,
// ONE barrier per kt. Block: 4 waves x 32 q-rows (2 strips) = 128 rows.
// 1D grid 512: id%8 = bh%8 (K/V XCD-local). Q,K: bf16 [b,h,2048,64];
// V: bf16 [b,h,64,2048]; O: bf16 [4096,1024].
__global__ __launch_bounds__(256) void attn_kernel(
    const __bf16* __restrict__ Q, const __bf16* __restrict__ Kb_,
    const __bf16* __restrict__ Vt, __bf16* __restrict__ O)
{
    __shared__ __align__(16) __bf16 Ks[2][64 * 64];
    __shared__ __align__(16) __bf16 Vs[2][64 * 64];
    __shared__ __align__(16) __bf16 p_lds[4][2][16][72];

    const int lane = threadIdx.x & 63;
    const int wave = threadIdx.x >> 6;
    const int quad = lane >> 4;
    const int l15  = lane & 15;
    const int bh = blockIdx.x & 31;   // id%8 = bh%8 -> XCD locality
    const int qt = blockIdx.x >> 5;   // 0..15 (128-row q tiles)
    const int b  = bh >> 4, h = bh & 15;

    const __bf16* Qh = Q   + (size_t)bh * 2048 * 64;
    const __bf16* Kh = Kb_ + (size_t)bh * 2048 * 64;
    const __bf16* Vh = Vt  + (size_t)bh * 64 * 2048;

    int srow[2], scol[2];
    #pragma unroll
    for (int i = 0; i < 2; ++i) {
        int L = (i * 4 + wave) * 64 + lane;
        int r = L >> 3, s = L & 7;
        srow[i] = r; scol[i] = (s ^ (r & 7)) * 8;
    }

    v8bf qf[2][2];
    #pragma unroll
    for (int s = 0; s < 2; ++s)
        #pragma unroll
        for (int ks = 0; ks < 2; ++ks)
            qf[s][ks] = *reinterpret_cast<const v8bf*>(
                Qh + (size_t)(qt * 128 + wave * 32 + s * 16 + l15) * 64 + ks * 32 + quad * 8);

    v4f o_acc[2][4];
    #pragma unroll
    for (int s = 0; s < 2; ++s)
        #pragma unroll
        for (int c = 0; c < 4; ++c) { v4f z = {0.f,0.f,0.f,0.f}; o_acc[s][c] = z; }
    float l_r[2][4];
    #pragma unroll
    for (int s = 0; s < 2; ++s)
        #pragma unroll
        for (int r = 0; r < 4; ++r) l_r[s][r] = 0.f;

    // Prologue: stage kt=0 into buf 0.
    #pragma unroll
    for (int i = 0; i < 2; ++i) {
        gl_lds16(Kh + (size_t)srow[i] * 64 + scol[i], &Ks[0][(i * 4 + wave) * 512]);
        gl_lds16(Vh + (size_t)srow[i] * 2048 + scol[i], &Vs[0][(i * 4 + wave) * 512]);
    }
    __syncthreads();

    for (int kt = 0; kt < 32; ++kt) {
        const int cur = kt & 1, nxt = cur ^ 1;
        const int ktn = (kt + 1) & 31;   // wraps on last iter (wasted DMA)
        #pragma unroll
        for (int i = 0; i < 2; ++i) {
            gl_lds16(Kh + (size_t)(ktn * 64 + srow[i]) * 64 + scol[i],
                     &Ks[nxt][(i * 4 + wave) * 512]);
            gl_lds16(Vh + (size_t)srow[i] * 2048 + ktn * 64 + scol[i],
                     &Vs[nxt][(i * 4 + wave) * 512]);
        }

        // S = Q @ K^T (scores in log2 domain via Q pre-scale).
        v4f s_t[2][4];
        #pragma unroll
        for (int s = 0; s < 2; ++s)
            #pragma unroll
            for (int c = 0; c < 4; ++c) { v4f z = {0.f,0.f,0.f,0.f}; s_t[s][c] = z; }
        #pragma unroll
        for (int ks = 0; ks < 2; ++ks) {
            v8bf kf[4];
            #pragma unroll
            for (int c = 0; c < 4; ++c) {
                const int R = c * 16 + l15;
                const int slot = (ks * 4 + quad) ^ (R & 7);
                kf[c] = *reinterpret_cast<const v8bf*>(&Ks[cur][R * 64 + slot * 8]);
            }
            #pragma unroll
            for (int c = 0; c < 4; ++c) {
                s_t[0][c] = __builtin_amdgcn_mfma_f32_16x16x32_bf16(qf[0][ks], kf[c], s_t[0][c], 0, 0, 0);
                s_t[1][c] = __builtin_amdgcn_mfma_f32_16x16x32_bf16(qf[1][ks], kf[c], s_t[1][c], 0, 0, 0);
            }
        }

        // p = 2^s; per-lane row-sum partials; stage P (wave-private, no barrier).
        #pragma unroll
        for (int s = 0; s < 2; ++s)
            #pragma unroll
            for (int r = 0; r < 4; ++r) {
                const float p0 = __builtin_exp2f(s_t[s][0][r]);
                const float p1 = __builtin_exp2f(s_t[s][1][r]);
                const float p2 = __builtin_exp2f(s_t[s][2][r]);
                const float p3 = __builtin_exp2f(s_t[s][3][r]);
                l_r[s][r] += (p0 + p1) + (p2 + p3);
                p_lds[wave][s][quad * 4 + r][0 * 16 + l15] = (__bf16)p0;
                p_lds[wave][s][quad * 4 + r][1 * 16 + l15] = (__bf16)p1;
                p_lds[wave][s][quad * 4 + r][2 * 16 + l15] = (__bf16)p2;
                p_lds[wave][s][quad * 4 + r][3 * 16 + l15] = (__bf16)p3;
            }

        // O += P @ V
        #pragma unroll
        for (int ks = 0; ks < 2; ++ks) {
            v8bf vf[4];
            #pragma unroll
            for (int c = 0; c < 4; ++c) {
                const int R = c * 16 + l15;
                const int slot = (ks * 4 + quad) ^ (R & 7);
                vf[c] = *reinterpret_cast<const v8bf*>(&Vs[cur][R * 64 + slot * 8]);
            }
            #pragma unroll
            for (int s = 0; s < 2; ++s) {
                v8bf pf = *reinterpret_cast<const v8bf*>(&p_lds[wave][s][l15][ks * 32 + quad * 8]);
                #pragma unroll
                for (int c = 0; c < 4; ++c)
                    o_acc[s][c] = __builtin_amdgcn_mfma_f32_16x16x32_bf16(pf, vf[c], o_acc[s][c], 0, 0, 0);
            }
        }
        __syncthreads();   // DMA kt+1 done + all reads of cur done
    }

    // Reduce l across 16 lanes per row; write O bf16 [b*2048+q, h*64+d].
    #pragma unroll
    for (int s = 0; s < 2; ++s)
        #pragma unroll
        for (int r = 0; r < 4; ++r) {
            float l = l_r[s][r];
            #pragma unroll
            for (int off = 1; off < 16; off <<= 1)
                l += __shfl_xor(l, off, 16);
            const float inv_l = 1.0f / l;
            const int qr = qt * 128 + wave * 32 + s * 16 + quad * 4 + r;
            #pragma unroll
            for (int c = 0; c < 4; ++c) {
                const int col = h * 64 + c * 16 + l15;
                O[(size_t)(b * 2048 + qr) * 1024 + col] = (__bf16)(o_acc[s][c][r] * inv_l);
            }
        }
}

extern "C" void kernel_launch(void* const* d_in, const int* in_sizes, int n_in,
                              void* d_out, int out_size, void* d_ws, size_t ws_size,
                              hipStream_t stream) {
    const float* q_in = (const float*)d_in[0];
    const float* k_in = (const float*)d_in[1];
    const float* v_in = (const float*)d_in[2];
    const float* Wq = (const float*)d_in[3];
    const float* bq = (const float*)d_in[4];
    const float* Wk = (const float*)d_in[5];
    const float* bk = (const float*)d_in[6];
    const float* Wv = (const float*)d_in[7];
    const float* bv = (const float*)d_in[8];
    const float* Wo = (const float*)d_in[9];
    const float* bo = (const float*)d_in[10];
    float* out = (float*)d_out;

    // Workspace (bf16 elements), 56 MiB. Ob aliases Abq (consumed before attn).
    __bf16* ws  = (__bf16*)d_ws;
    __bf16* Abq = ws;                  // [4096,1024]
    __bf16* Abk = Abq + 4194304;
    __bf16* Abv = Abk + 4194304;
    __bf16* Qb  = Abv + 4194304;       // [2,16,2048,64]
    __bf16* Kb  = Qb  + 4194304;
    __bf16* Vb  = Kb  + 4194304;       // [2,16,64,2048]
    __bf16* Wqb = Vb  + 4194304;       // [1024,1024] x4
    __bf16* Wkb = Wqb + 1048576;
    __bf16* Wvb = Wkb + 1048576;
    __bf16* Wob = Wvb + 1048576;
    __bf16* Ob  = Abq;                 // alias

    cvt_w<<<dim3(512, 4), 256, 0, stream>>>(Wq, Wk, Wv, Wo, Wqb, Wkb, Wvb, Wob);
    cvt_in<<<dim3(2048, 3), 256, 0, stream>>>(q_in, k_in, v_in, Abq, Abk, Abv);

    qkv_gemm<<<1536, 256, 0, stream>>>(
        Abq, Abk, Abv, Wqb, Wkb, Wvb, bq, bk, bv, Qb, Kb, Vb);

    attn_kernel<<<512, 256, 0, stream>>>(Qb, Kb, Vb, Ob);

    out_gemm<<<512, 256, 0, stream>>>(Ob, Wob, bo, out);
}